// Round 15
// baseline (73.039 us; speedup 1.0000x reference)
//
#include <hip/hip_runtime.h>
#include <math.h>

#define N_GRAPHS 4096
#define LATENT 32
#define BLK 256
#define ZSTRIDE 80   // bytes per bf16 z-row: 64B data + 16B pad (16B-aligned rows)
#define GRID_ATTN 2048

typedef short bf16x8 __attribute__((ext_vector_type(8)));
typedef float f32x4  __attribute__((ext_vector_type(4)));
typedef int   i32x4  __attribute__((ext_vector_type(4)));

// DPP row_shr accumulate; after steps 1,2,4,8 lane 15 of each 16-group holds the group sum
template<int CTRL>
__device__ __forceinline__ float dpp_shr_add(float x) {
    int y = __builtin_amdgcn_update_dpp(0, __float_as_int(x), CTRL, 0xf, 0xf, false);
    return x + __int_as_float(y);
}

__device__ __forceinline__ float tanh_fast(float x) {
    // tanh(x) = 1 - 2/(exp(2x)+1); +/-inf limits exact
    float e2 = __expf(2.f * x);
    return 1.f - 2.f * __builtin_amdgcn_rcpf(e2 + 1.f);
}

__device__ __forceinline__ unsigned short f32_to_bf16(float f) {
    unsigned int u = __float_as_uint(f);
    u += 0x7fff + ((u >> 16) & 1);   // RNE
    return (unsigned short)(u >> 16);
}

__global__ __launch_bounds__(256) void zero_ws_kernel(float4* __restrict__ ws) {
    ws[blockIdx.x * 256 + threadIdx.x] = float4{0.f, 0.f, 0.f, 0.f};
}

// Fused: per-node attention score (bf16 MFMA) + exp + segmented weighted sums.
// r15 vs r14: persistent grid-stride blocks (2048) with 1-deep prefetch.
// Each tile's z/batch loads are issued during the PREVIOUS tile's MFMA+sweep
// (~2000 cyc of cover for ~900 cyc HBM latency) -> load latency leaves the
// per-tile critical path. part un-aliased from w1T so w1T survives tiles.
__global__ __launch_bounds__(BLK, 2) void attn_seg_kernel(
    const float* __restrict__ z, const int* __restrict__ batch,
    const float* __restrict__ w1, const float* __restrict__ b1,
    const float* __restrict__ w2, const float* __restrict__ b2v,
    float* __restrict__ se, float* __restrict__ sez, int n)
{
    // layout (bytes):
    //     0 .. 20480  zb   [256][ZSTRIDE] bf16 z rows (per tile)
    // 20480 .. 21504  gls  [256] i32
    // 21504 .. 22528  ev   [256] f32
    // 22528 .. 25088  w1T  [32][ZSTRIDE] bf16 (staged once, lives all tiles)
    // 25088 .. 27392  part [16][36] f32 (col 32 = e, col 33 = graph id bits)
    // 27392 .. 28416  tab  [256] f32
    __shared__ __align__(16) char smem[28416];
    char*  zb   = smem;
    int*   gls  = (int*)(smem + 20480);
    float* ev   = (float*)(smem + 21504);
    char*  w1T  = smem + 22528;
    float* part = (float*)(smem + 25088);
    float* tab  = (float*)(smem + 27392);

    const int t = threadIdx.x;
    const int lane = t & 63, w = t >> 6;
    const int mrow = lane & 15, grp = lane >> 4;

    // small per-lane gathers (128B regions, L1-hot)
    const float b1a = b1[mrow], b1b = b1[mrow + 16];
    const float w2a = w2[mrow], w2b = w2[mrow + 16];
    const float b2s = b2v[0];

    // ---- stage W1^T as bf16 once: w1T[n][k], 1024 elems / 256 threads ----
    #pragma unroll
    for (int i = 0; i < 4; ++i) {
        int idx = t*4 + i, k = idx >> 5, nc = idx & 31;
        *(unsigned short*)(w1T + nc*ZSTRIDE + k*2) = f32_to_bf16(w1[k*LATENT + nc]);
    }

    const int ntiles = (n + BLK - 1) / BLK;
    const float4* z4 = (const float4*)z;
    const size_t max_f4 = (size_t)n * 8;

    float4 v4s[8];          // prefetched z (float4 #(q*256+t) of tile region)
    int    gpref;           // prefetched batch id for this thread's node
    // prologue: issue loads for first tile
    {
        const size_t blk_f4 = (size_t)blockIdx.x * 2048;
        #pragma unroll
        for (int q = 0; q < 8; ++q) {
            size_t f = blk_f4 + q*256 + t;
            if (f >= max_f4) f = max_f4 - 1;
            v4s[q] = z4[f];
        }
        int nd0 = blockIdx.x * BLK + t;
        gpref = batch[(nd0 < n) ? nd0 : (n - 1)];
    }

    for (int tile = blockIdx.x; tile < ntiles; tile += GRID_ATTN) {
        const int nd = tile * BLK + t;

        // ---- write prefetched regs to LDS (zb/gls free: prev sweep done) ----
        gls[t] = gpref;
        #pragma unroll
        for (int q = 0; q < 8; ++q) {
            int lo, hi;
            asm("v_cvt_pk_bf16_f32 %0, %1, %2" : "=v"(lo) : "v"(v4s[q].x), "v"(v4s[q].y));
            asm("v_cvt_pk_bf16_f32 %0, %1, %2" : "=v"(hi) : "v"(v4s[q].z), "v"(v4s[q].w));
            const int node = q*32 + (t >> 3), quad = t & 7;
            *(int2*)(zb + node*ZSTRIDE + quad*8) = int2{lo, hi};
        }
        // ---- issue next tile's loads; they fly under MFMA+sweep ----
        const int nxt = tile + GRID_ATTN;
        if (nxt < ntiles) {
            const size_t blk_f4 = (size_t)nxt * 2048;
            #pragma unroll
            for (int q = 0; q < 8; ++q) {
                size_t f = blk_f4 + q*256 + t;
                if (f >= max_f4) f = max_f4 - 1;
                v4s[q] = z4[f];
            }
            int ndn = nxt * BLK + t;
            gpref = batch[(ndn < n) ? ndn : (n - 1)];
        }
        __syncthreads();   // B1: zb + gls visible

        // ---- MFMA: per wave, 64 nodes x 32 hidden, K=32 ----
        bf16x8 A[4];
        #pragma unroll
        for (int T = 0; T < 4; ++T)
            A[T] = *(const bf16x8*)(zb + (w*64 + T*16 + mrow)*ZSTRIDE + grp*16);
        bf16x8 Bh0 = *(const bf16x8*)(w1T + mrow*ZSTRIDE + grp*16);        // hidden 0-15
        bf16x8 Bh1 = *(const bf16x8*)(w1T + (mrow+16)*ZSTRIDE + grp*16);   // hidden 16-31

        const f32x4 c0 = {b1a, b1a, b1a, b1a};
        const f32x4 c1 = {b1b, b1b, b1b, b1b};
        float p[4][4];
        #pragma unroll
        for (int T = 0; T < 4; ++T) {
            f32x4 d0 = __builtin_amdgcn_mfma_f32_16x16x32_bf16(A[T], Bh0, c0, 0, 0, 0);
            f32x4 d1 = __builtin_amdgcn_mfma_f32_16x16x32_bf16(A[T], Bh1, c1, 0, 0, 0);
            #pragma unroll
            for (int r = 0; r < 4; ++r)
                p[T][r] = tanh_fast(d0[r]) * w2a + tanh_fast(d1[r]) * w2b;
        }
        #pragma unroll
        for (int T = 0; T < 4; ++T) {
            #pragma unroll
            for (int r = 0; r < 4; ++r) {
                float v = p[T][r];
                v = dpp_shr_add<0x111>(v);
                v = dpp_shr_add<0x112>(v);
                v = dpp_shr_add<0x114>(v);
                v = dpp_shr_add<0x118>(v);
                p[T][r] = v;
            }
        }
        if (mrow == 15) {  // lane 16*grp+15 holds sums for node-rows grp*4+r of tile T
            #pragma unroll
            for (int T = 0; T < 4; ++T)
                *(f32x4*)(tab + w*64 + T*16 + grp*4) = f32x4{p[T][0], p[T][1], p[T][2], p[T][3]};
        }
        __syncthreads();   // B2: alpha table visible

        // node n=lane: T=n>>4, g=(n>>2)&3, r=n&3
        float alpha = tab[w*64 + (lane>>4)*16 + ((lane>>2)&3)*4 + (lane&3)] + b2s;
        // global-max subtraction cancels in per-graph normalization; skip it.
        const float e = (nd < n) ? __expf(alpha) : 0.f;
        ev[t] = e;
        __syncthreads();   // B3: ev visible

        // register-batched segmented sweep: 16 chunks x 16 nodes.
        {
            const int c  = t >> 4;
            const int kk = t & 15;
            const int base = c * 16;
            const f32x4 e0 = *(const f32x4*)(ev + base);
            const f32x4 e1 = *(const f32x4*)(ev + base + 4);
            const f32x4 e2 = *(const f32x4*)(ev + base + 8);
            const f32x4 e3 = *(const f32x4*)(ev + base + 12);
            const i32x4 g0 = *(const i32x4*)(gls + base);
            const i32x4 g1 = *(const i32x4*)(gls + base + 4);
            const i32x4 g2 = *(const i32x4*)(gls + base + 8);
            const i32x4 g3 = *(const i32x4*)(gls + base + 12);

            float a0 = 0.f, a1 = 0.f;
            int gc = g0[0];
            #pragma unroll
            for (int j = 0; j < 16; ++j) {
                const int   gn = (j < 4) ? g0[j&3] : (j < 8) ? g1[j&3] : (j < 12) ? g2[j&3] : g3[j&3];
                const float ej = (j < 4) ? e0[j&3] : (j < 8) ? e1[j&3] : (j < 12) ? e2[j&3] : e3[j&3];
                const int d = *(const int*)(zb + (base + j)*ZSTRIDE + kk*4);
                if (gn != gc) {   // rare: graph boundary inside chunk
                    atomicAdd(&sez[gc*LATENT + 2*kk],     a0);
                    atomicAdd(&sez[gc*LATENT + 2*kk + 1], a1);
                    a0 = a1 = 0.f; gc = gn;
                }
                a0 = fmaf(ej, __int_as_float((unsigned)d << 16),        a0);
                a1 = fmaf(ej, __int_as_float((unsigned)d & 0xffff0000u), a1);
            }
            *(float2*)(part + c*36 + 2*kk) = float2{a0, a1};

            if (kk == 0) {   // e-column sweep for chunk c, straight from registers
                float ae = 0.f;
                int ge = g0[0];
                #pragma unroll
                for (int j = 0; j < 16; ++j) {
                    const int   gn = (j < 4) ? g0[j&3] : (j < 8) ? g1[j&3] : (j < 12) ? g2[j&3] : g3[j&3];
                    const float ej = (j < 4) ? e0[j&3] : (j < 8) ? e1[j&3] : (j < 12) ? e2[j&3] : e3[j&3];
                    if (gn != ge) { atomicAdd(&se[ge], ae); ae = 0.f; ge = gn; }
                    ae += ej;
                }
                part[c*36 + 32] = ae;
                ((int*)part)[c*36 + 33] = g3[3];   // chunk-final graph id
            }
        }
        __syncthreads();   // B4: part staged; zb/gls/ev free for next tile

        // combine 16 chunk partials per column -> ~1 atomic per column per block
        if (t < 33) {
            const int col = t;               // 32 = e column
            float acc = part[col];           // chunk 0
            int gc = ((const int*)part)[33];
            #pragma unroll
            for (int cc = 1; cc < 16; ++cc) {
                const int gn = ((const int*)part)[cc*36 + 33];
                if (gn != gc) {
                    if (col < 32) atomicAdd(&sez[gc*LATENT + col], acc);
                    else          atomicAdd(&se[gc], acc);
                    acc = 0.f; gc = gn;
                }
                acc += part[cc*36 + col];
            }
            if (col < 32) atomicAdd(&sez[gc*LATENT + col], acc);
            else          atomicAdd(&se[gc], acc);
        }
        // next iteration's B1 guarantees combine's part reads finish before
        // the next sweep overwrites part (B1..B3 are in between).
    }
}

// One wave per graph: graph_z = sez/(se+1e-8); 32->128->64->1 MLP with sigmoid.
__global__ __launch_bounds__(64) void mlp_kernel(
    const float* __restrict__ se, const float* __restrict__ sez,
    const float* __restrict__ m1w, const float* __restrict__ m1b,
    const float* __restrict__ m2w, const float* __restrict__ m2b,
    const float* __restrict__ m3w, const float* __restrict__ m3b,
    float* __restrict__ out)
{
    int gidx = blockIdx.x;
    int lane = threadIdx.x;
    float inv = 1.f / (se[gidx] + 1e-8f);
    float gz = (lane < LATENT) ? sez[gidx*LATENT + lane] * inv : 0.f;

    float a0 = m1b[lane], a1 = m1b[lane + 64];
    #pragma unroll
    for (int k = 0; k < LATENT; ++k) {
        float zk = __shfl(gz, k);
        a0 = fmaf(zk, m1w[k*128 + lane], a0);
        a1 = fmaf(zk, m1w[k*128 + lane + 64], a1);
    }
    a0 = fmaxf(a0, 0.f); a1 = fmaxf(a1, 0.f);

    float b = m2b[lane];
    #pragma unroll
    for (int k = 0; k < 64; ++k) {
        float xk = __shfl(a0, k);
        b = fmaf(xk, m2w[k*64 + lane], b);
    }
    #pragma unroll
    for (int k = 0; k < 64; ++k) {
        float xk = __shfl(a1, k);
        b = fmaf(xk, m2w[(k+64)*64 + lane], b);
    }
    b = fmaxf(b, 0.f);

    float p = b * m3w[lane];
    #pragma unroll
    for (int s = 32; s >= 1; s >>= 1)
        p += __shfl_xor(p, s);
    if (lane == 0)
        out[gidx] = 1.f / (1.f + __expf(-(p + m3b[0])));
}

extern "C" void kernel_launch(void* const* d_in, const int* in_sizes, int n_in,
                              void* d_out, int out_size, void* d_ws, size_t ws_size,
                              hipStream_t stream)
{
    const float* z    = (const float*)d_in[0];
    const int*   batch= (const int*)d_in[1];
    const float* aw1  = (const float*)d_in[2];
    const float* ab1  = (const float*)d_in[3];
    const float* aw2  = (const float*)d_in[4];
    const float* ab2  = (const float*)d_in[5];
    const float* m1w  = (const float*)d_in[6];
    const float* m1b  = (const float*)d_in[7];
    const float* m2w  = (const float*)d_in[8];
    const float* m2b  = (const float*)d_in[9];
    const float* m3w  = (const float*)d_in[10];
    const float* m3b  = (const float*)d_in[11];
    float* out = (float*)d_out;

    int n = in_sizes[0] / LATENT;   // 2,000,000 nodes

    float* se  = (float*)d_ws;          // [4096]
    float* sez = se + N_GRAPHS;         // [4096][32]

    // N_GRAPHS*33 floats = 135168 floats = 33792 float4 = 132 blocks * 256
    zero_ws_kernel<<<132, 256, 0, stream>>>((float4*)d_ws);

    attn_seg_kernel<<<GRID_ATTN, BLK, 0, stream>>>(z, batch, aw1, ab1, aw2, ab2, se, sez, n);
    mlp_kernel<<<N_GRAPHS, 64, 0, stream>>>(se, sez, m1w, m1b, m2w, m2b, m3w, m3b, out);
}

// Round 16
// 62.202 us; speedup vs baseline: 1.1742x; 1.1742x over previous
//
#include <hip/hip_runtime.h>
#include <math.h>

#define N_GRAPHS 4096
#define LATENT 32
#define BLK 256
#define ZSTRIDE 80   // bytes per bf16 z-row: 64B data + 16B pad (16B-aligned rows)

typedef short bf16x8 __attribute__((ext_vector_type(8)));
typedef float f32x4  __attribute__((ext_vector_type(4)));
typedef int   i32x4  __attribute__((ext_vector_type(4)));

// DPP row_shr accumulate; after steps 1,2,4,8 lane 15 of each 16-group holds the group sum
template<int CTRL>
__device__ __forceinline__ float dpp_shr_add(float x) {
    int y = __builtin_amdgcn_update_dpp(0, __float_as_int(x), CTRL, 0xf, 0xf, false);
    return x + __int_as_float(y);
}

__device__ __forceinline__ float tanh_fast(float x) {
    // tanh(x) = 1 - 2/(exp(2x)+1); +/-inf limits exact
    float e2 = __expf(2.f * x);
    return 1.f - 2.f * __builtin_amdgcn_rcpf(e2 + 1.f);
}

__device__ __forceinline__ unsigned short f32_to_bf16(float f) {
    unsigned int u = __float_as_uint(f);
    u += 0x7fff + ((u >> 16) & 1);   // RNE
    return (unsigned short)(u >> 16);
}

__global__ __launch_bounds__(256) void zero_ws_kernel(float4* __restrict__ ws) {
    ws[blockIdx.x * 256 + threadIdx.x] = float4{0.f, 0.f, 0.f, 0.f};
}

// Fused: per-node attention score (bf16 MFMA) + exp + segmented weighted sums.
// r16 = r14 revert (62.3us best). r15's persistent prefetch regressed (+10.7us):
// prefetch registers (~33 VGPR) live across 4 barriers + vmcnt(0) drain at the
// stage-write with nothing to overlap. Structure summary:
//  - coalesced z load (wave = 1KB contiguous), cvt to bf16, LDS [node][quad]
//  - z@W1 via mfma_f32_16x16x32_bf16 (A/B same slot->k map -> layout cancels)
//  - DPP row_shr reduce for h@w2; alpha table in LDS
//  - register-batched segmented sweep (16 chunks x 16 nodes, e/g in regs)
//  - cross-chunk LDS combine -> ~40 atomics/block
__global__ __launch_bounds__(BLK, 2) void attn_seg_kernel(
    const float* __restrict__ z, const int* __restrict__ batch,
    const float* __restrict__ w1, const float* __restrict__ b1,
    const float* __restrict__ w2, const float* __restrict__ b2v,
    float* __restrict__ se, float* __restrict__ sez, int n)
{
    // layout (bytes):
    //     0 .. 20480  zb   [256][ZSTRIDE] bf16 z rows (lives whole kernel)
    // 20480 .. 21504  gls  [256] i32
    // 21504 .. 22528  ev   [256] f32
    // 22528 .. 25088  w1T  [32][ZSTRIDE] bf16 (dead after MFMA)
    //                      ALIASED by part [16][36] f32 (phase 2; col 32 = e,
    //                      col 33 = chunk-final graph id)
    // 25088 .. 26112  tab  [256] f32 (dead after alpha read)
    __shared__ __align__(16) char smem[26112];
    char*  zb   = smem;
    int*   gls  = (int*)(smem + 20480);
    float* ev   = (float*)(smem + 21504);
    char*  w1T  = smem + 22528;
    float* part = (float*)(smem + 22528);
    float* tab  = (float*)(smem + 25088);

    const int t = threadIdx.x;
    const int lane = t & 63, w = t >> 6;
    const int mrow = lane & 15, grp = lane >> 4;
    const int nd = blockIdx.x * BLK + t;
    const int ndL = (nd < n) ? nd : (n - 1);    // clamp; clamped rows get e=0
    gls[t] = batch[ndL];

    // small per-lane gathers (128B regions, L1-hot)
    const float b1a = b1[mrow], b1b = b1[mrow + 16];
    const float w2a = w2[mrow], w2b = w2[mrow + 16];

    // ---- coalesced z staging: block region = 2048 float4s; thread t, chunk q
    // loads float4 #(q*256+t) -> per-wave 1KB contiguous ----
    {
        const size_t blk_f4 = (size_t)blockIdx.x * 2048;
        const size_t max_f4 = (size_t)n * 8;
        const float4* z4 = (const float4*)z;
        float4 v4s[8];
        #pragma unroll
        for (int q = 0; q < 8; ++q) {
            size_t f = blk_f4 + q*256 + t;
            if (f >= max_f4) f = max_f4 - 1;   // last block only; finite values
            v4s[q] = z4[f];
        }
        #pragma unroll
        for (int q = 0; q < 8; ++q) {
            int lo, hi;
            asm("v_cvt_pk_bf16_f32 %0, %1, %2" : "=v"(lo) : "v"(v4s[q].x), "v"(v4s[q].y));
            asm("v_cvt_pk_bf16_f32 %0, %1, %2" : "=v"(hi) : "v"(v4s[q].z), "v"(v4s[q].w));
            const int node = q*32 + (t >> 3), quad = t & 7;
            *(int2*)(zb + node*ZSTRIDE + quad*8) = int2{lo, hi};
        }
    }

    // ---- stage W1^T as bf16: w1T[n][k], 1024 elems / 256 threads ----
    #pragma unroll
    for (int i = 0; i < 4; ++i) {
        int idx = t*4 + i, k = idx >> 5, nc = idx & 31;
        *(unsigned short*)(w1T + nc*ZSTRIDE + k*2) = f32_to_bf16(w1[k*LATENT + nc]);
    }
    __syncthreads();   // B1: z-tile + w1T + gls visible

    // ---- MFMA: per wave, 64 nodes x 32 hidden, K=32 ----
    bf16x8 A[4];
    #pragma unroll
    for (int T = 0; T < 4; ++T)
        A[T] = *(const bf16x8*)(zb + (w*64 + T*16 + mrow)*ZSTRIDE + grp*16);
    bf16x8 Bh0 = *(const bf16x8*)(w1T + mrow*ZSTRIDE + grp*16);          // hidden 0-15
    bf16x8 Bh1 = *(const bf16x8*)(w1T + (mrow+16)*ZSTRIDE + grp*16);     // hidden 16-31

    const f32x4 c0 = {b1a, b1a, b1a, b1a};
    const f32x4 c1 = {b1b, b1b, b1b, b1b};
    float p[4][4];
    #pragma unroll
    for (int T = 0; T < 4; ++T) {
        f32x4 d0 = __builtin_amdgcn_mfma_f32_16x16x32_bf16(A[T], Bh0, c0, 0, 0, 0);
        f32x4 d1 = __builtin_amdgcn_mfma_f32_16x16x32_bf16(A[T], Bh1, c1, 0, 0, 0);
        #pragma unroll
        for (int r = 0; r < 4; ++r)
            p[T][r] = tanh_fast(d0[r]) * w2a + tanh_fast(d1[r]) * w2b;
    }
    // sum the 16 lanes of each group (hidden cols); total lands in lane 15 of group
    #pragma unroll
    for (int T = 0; T < 4; ++T) {
        #pragma unroll
        for (int r = 0; r < 4; ++r) {
            float v = p[T][r];
            v = dpp_shr_add<0x111>(v);
            v = dpp_shr_add<0x112>(v);
            v = dpp_shr_add<0x114>(v);
            v = dpp_shr_add<0x118>(v);
            p[T][r] = v;
        }
    }
    if (mrow == 15) {  // lane 16*grp+15 holds sums for node-rows grp*4+r of tile T
        #pragma unroll
        for (int T = 0; T < 4; ++T)
            *(f32x4*)(tab + w*64 + T*16 + grp*4) = f32x4{p[T][0], p[T][1], p[T][2], p[T][3]};
    }
    __syncthreads();   // B2: alpha table visible

    // node n=lane: T=n>>4, g=(n>>2)&3, r=n&3
    float alpha = tab[w*64 + (lane>>4)*16 + ((lane>>2)&3)*4 + (lane&3)] + b2v[0];
    // global-max subtraction cancels in per-graph normalization; skip it.
    const float e = (nd < n) ? __expf(alpha) : 0.f;
    ev[t] = e;
    __syncthreads();   // B3: ev visible; w1T/tab reads done (part may overwrite)

    // register-batched segmented sweep: 16 chunks x 16 nodes.
    // thread (c = t>>4, kk = t&15) sums columns 2kk, 2kk+1 over its chunk.
    {
        const int c  = t >> 4;
        const int kk = t & 15;
        const int base = c * 16;
        const f32x4 e0 = *(const f32x4*)(ev + base);
        const f32x4 e1 = *(const f32x4*)(ev + base + 4);
        const f32x4 e2 = *(const f32x4*)(ev + base + 8);
        const f32x4 e3 = *(const f32x4*)(ev + base + 12);
        const i32x4 g0 = *(const i32x4*)(gls + base);
        const i32x4 g1 = *(const i32x4*)(gls + base + 4);
        const i32x4 g2 = *(const i32x4*)(gls + base + 8);
        const i32x4 g3 = *(const i32x4*)(gls + base + 12);

        float a0 = 0.f, a1 = 0.f;
        int gc = g0[0];
        #pragma unroll
        for (int j = 0; j < 16; ++j) {
            const int   gn = (j < 4) ? g0[j&3] : (j < 8) ? g1[j&3] : (j < 12) ? g2[j&3] : g3[j&3];
            const float ej = (j < 4) ? e0[j&3] : (j < 8) ? e1[j&3] : (j < 12) ? e2[j&3] : e3[j&3];
            const int d = *(const int*)(zb + (base + j)*ZSTRIDE + kk*4);
            if (gn != gc) {   // rare: graph boundary inside chunk
                atomicAdd(&sez[gc*LATENT + 2*kk],     a0);
                atomicAdd(&sez[gc*LATENT + 2*kk + 1], a1);
                a0 = a1 = 0.f; gc = gn;
            }
            a0 = fmaf(ej, __int_as_float((unsigned)d << 16),        a0);
            a1 = fmaf(ej, __int_as_float((unsigned)d & 0xffff0000u), a1);
        }
        *(float2*)(part + c*36 + 2*kk) = float2{a0, a1};

        if (kk == 0) {   // e-column sweep for chunk c, straight from registers
            float ae = 0.f;
            int ge = g0[0];
            #pragma unroll
            for (int j = 0; j < 16; ++j) {
                const int   gn = (j < 4) ? g0[j&3] : (j < 8) ? g1[j&3] : (j < 12) ? g2[j&3] : g3[j&3];
                const float ej = (j < 4) ? e0[j&3] : (j < 8) ? e1[j&3] : (j < 12) ? e2[j&3] : e3[j&3];
                if (gn != ge) { atomicAdd(&se[ge], ae); ae = 0.f; ge = gn; }
                ae += ej;
            }
            part[c*36 + 32] = ae;
            ((int*)part)[c*36 + 33] = g3[3];   // chunk-final graph id
        }
    }
    __syncthreads();   // B4: part staged

    // combine 16 chunk partials per column -> ~1 atomic per column per block
    if (t < 33) {
        const int col = t;               // 32 = e column
        float acc = part[col];           // chunk 0
        int gc = ((const int*)part)[33];
        #pragma unroll
        for (int cc = 1; cc < 16; ++cc) {
            const int gn = ((const int*)part)[cc*36 + 33];
            if (gn != gc) {
                if (col < 32) atomicAdd(&sez[gc*LATENT + col], acc);
                else          atomicAdd(&se[gc], acc);
                acc = 0.f; gc = gn;
            }
            acc += part[cc*36 + col];
        }
        if (col < 32) atomicAdd(&sez[gc*LATENT + col], acc);
        else          atomicAdd(&se[gc], acc);
    }
}

// One wave per graph: graph_z = sez/(se+1e-8); 32->128->64->1 MLP with sigmoid.
__global__ __launch_bounds__(64) void mlp_kernel(
    const float* __restrict__ se, const float* __restrict__ sez,
    const float* __restrict__ m1w, const float* __restrict__ m1b,
    const float* __restrict__ m2w, const float* __restrict__ m2b,
    const float* __restrict__ m3w, const float* __restrict__ m3b,
    float* __restrict__ out)
{
    int gidx = blockIdx.x;
    int lane = threadIdx.x;
    float inv = 1.f / (se[gidx] + 1e-8f);
    float gz = (lane < LATENT) ? sez[gidx*LATENT + lane] * inv : 0.f;

    float a0 = m1b[lane], a1 = m1b[lane + 64];
    #pragma unroll
    for (int k = 0; k < LATENT; ++k) {
        float zk = __shfl(gz, k);
        a0 = fmaf(zk, m1w[k*128 + lane], a0);
        a1 = fmaf(zk, m1w[k*128 + lane + 64], a1);
    }
    a0 = fmaxf(a0, 0.f); a1 = fmaxf(a1, 0.f);

    float b = m2b[lane];
    #pragma unroll
    for (int k = 0; k < 64; ++k) {
        float xk = __shfl(a0, k);
        b = fmaf(xk, m2w[k*64 + lane], b);
    }
    #pragma unroll
    for (int k = 0; k < 64; ++k) {
        float xk = __shfl(a1, k);
        b = fmaf(xk, m2w[(k+64)*64 + lane], b);
    }
    b = fmaxf(b, 0.f);

    float p = b * m3w[lane];
    #pragma unroll
    for (int s = 32; s >= 1; s >>= 1)
        p += __shfl_xor(p, s);
    if (lane == 0)
        out[gidx] = 1.f / (1.f + __expf(-(p + m3b[0])));
}

extern "C" void kernel_launch(void* const* d_in, const int* in_sizes, int n_in,
                              void* d_out, int out_size, void* d_ws, size_t ws_size,
                              hipStream_t stream)
{
    const float* z    = (const float*)d_in[0];
    const int*   batch= (const int*)d_in[1];
    const float* aw1  = (const float*)d_in[2];
    const float* ab1  = (const float*)d_in[3];
    const float* aw2  = (const float*)d_in[4];
    const float* ab2  = (const float*)d_in[5];
    const float* m1w  = (const float*)d_in[6];
    const float* m1b  = (const float*)d_in[7];
    const float* m2w  = (const float*)d_in[8];
    const float* m2b  = (const float*)d_in[9];
    const float* m3w  = (const float*)d_in[10];
    const float* m3b  = (const float*)d_in[11];
    float* out = (float*)d_out;

    int n = in_sizes[0] / LATENT;   // 2,000,000 nodes

    float* se  = (float*)d_ws;          // [4096]
    float* sez = se + N_GRAPHS;         // [4096][32]

    // N_GRAPHS*33 floats = 135168 floats = 33792 float4 = 132 blocks * 256
    zero_ws_kernel<<<132, 256, 0, stream>>>((float4*)d_ws);

    int blocks = (n + BLK - 1) / BLK;
    attn_seg_kernel<<<blocks, BLK, 0, stream>>>(z, batch, aw1, ab1, aw2, ab2, se, sez, n);
    mlp_kernel<<<N_GRAPHS, 64, 0, stream>>>(se, sez, m1w, m1b, m2w, m2b, m3w, m3b, out);
}